// Round 1
// baseline (1614.862 us; speedup 1.0000x reference)
//
#include <hip/hip_runtime.h>

#define NN 20000
#define NE 160000

typedef __bf16 bf16x8 __attribute__((ext_vector_type(8)));
typedef float f32x4 __attribute__((ext_vector_type(4)));

union U16B { uint4 v; unsigned short s[8]; };

__device__ __forceinline__ float b2f(unsigned short u) {
  return __uint_as_float(((unsigned int)u) << 16);
}
__device__ __forceinline__ unsigned short f2b(float f) {
  unsigned int x = __float_as_uint(f);
  x += 0x7fffu + ((x >> 16) & 1u);
  return (unsigned short)(x >> 16);
}
__device__ __forceinline__ float gelu_f(float v) {
  return 0.5f * v * (1.f + erff(v * 0.70710678118654752f));
}
__device__ __forceinline__ float lrelu(float v) { return v > 0.f ? v : 0.2f * v; }

// async global->LDS: 16B per lane, LDS dest = wave-uniform base + lane*16
typedef __attribute__((address_space(3))) unsigned char lds_uc;
typedef __attribute__((address_space(1))) const unsigned char glb_uc;
__device__ __forceinline__ void gld16(const void* g, void* l) {
  __builtin_amdgcn_global_load_lds((glb_uc*)g, (lds_uc*)l, 16, 0, 0);
}

// ---------------- input dtype detection ----------------
__global__ void detect_k(const unsigned short* __restrict__ w, int* __restrict__ flag) {
  __shared__ int bad;
  if (threadIdx.x == 0) bad = 0;
  __syncthreads();
  int cnt = 0;
  for (int i = threadIdx.x; i < 4096; i += 256) {
    unsigned int e = (w[i] >> 7) & 0xFFu;
    if (e < 100u || e > 154u) cnt++;
  }
  atomicAdd(&bad, cnt);
  __syncthreads();
  if (threadIdx.x == 0) *flag = (bad > 200) ? 1 : 0;   // 1 = inputs are fp32
}

// Normalize an input tensor to bf16 workspace copy.
__global__ void conv_k(const void* __restrict__ src, unsigned short* __restrict__ dst,
                       int n, const int* __restrict__ flag) {
  int i = blockIdx.x * blockDim.x + threadIdx.x;
  if (i >= n) return;
  if (*flag) dst[i] = f2b(((const float*)src)[i]);
  else       dst[i] = ((const unsigned short*)src)[i];
}

// Convert + transpose weight: src [K][C] (fp32 or bf16) -> dst [C][K] bf16.
__global__ __launch_bounds__(256) void convT_k(const void* __restrict__ src,
                                               unsigned short* __restrict__ dst,
                                               int K, int C, const int* __restrict__ flag) {
  __shared__ unsigned short t[32][33];
  int c0 = blockIdx.x * 32, k0 = blockIdx.y * 32;
  int x = threadIdx.x, y0 = threadIdx.y;   // blockDim (32, 8)
  int isf32 = *flag;
#pragma unroll
  for (int yy = y0; yy < 32; yy += 8) {
    size_t idx = (size_t)(k0 + yy) * C + (c0 + x);
    unsigned short v;
    if (isf32) v = f2b(((const float*)src)[idx]);
    else       v = ((const unsigned short*)src)[idx];
    t[yy][x] = v;
  }
  __syncthreads();
#pragma unroll
  for (int yy = y0; yy < 32; yy += 8) {
    dst[(size_t)(c0 + yy) * K + (k0 + x)] = t[x][yy];
  }
}

// ---------------- CSR build (dst-sorted) ----------------
__global__ void hist_k(const int* __restrict__ dst, int* __restrict__ deg) {
  int e = blockIdx.x * blockDim.x + threadIdx.x;
  if (e < NE) atomicAdd(&deg[dst[e]], 1);
}

__global__ __launch_bounds__(1024) void scan_k(const int* __restrict__ deg,
                                               int* __restrict__ indptr,
                                               int* __restrict__ cursor) {
  __shared__ int buf[1024];
  __shared__ int carryS;
  int tid = threadIdx.x;
  if (tid == 0) { carryS = 0; indptr[0] = 0; }
  __syncthreads();
  for (int base = 0; base < NN; base += 1024) {
    int i = base + tid;
    int v = (i < NN) ? deg[i] : 0;
    buf[tid] = v;
    __syncthreads();
    for (int off = 1; off < 1024; off <<= 1) {
      int t = (tid >= off) ? buf[tid - off] : 0;
      __syncthreads();
      buf[tid] += t;
      __syncthreads();
    }
    int c = carryS;
    if (i < NN) {
      indptr[i + 1] = c + buf[tid];
      cursor[i] = c + buf[tid] - v;   // exclusive
    }
    __syncthreads();
    if (tid == 0) carryS = c + buf[1023];
    __syncthreads();
  }
}

__global__ void scatter_k(const int* __restrict__ dst, int* __restrict__ cursor,
                          int* __restrict__ eidx) {
  int e = blockIdx.x * blockDim.x + threadIdx.x;
  if (e < NE) {
    int p = atomicAdd(&cursor[dst[e]], 1);
    eidx[p] = e;
  }
}

// ---------------- bf16 MFMA GEMM (m97 structure: 128x128x32, global_load_lds) ----
// A [M][K] bf16 (rows padded so staging of ceil(M/128)*128 rows is in-bounds)
// Bt [N][K] bf16 (pre-transposed weights), C [M][ldC] bf16
__global__ __launch_bounds__(256) void gemm_k(const unsigned short* __restrict__ A,
                                              const unsigned short* __restrict__ Bt,
                                              unsigned short* __restrict__ C,
                                              int M, int K, int ldC) {
  __shared__ unsigned short As[128 * 32];
  __shared__ unsigned short Bs[128 * 32];
  int tid = threadIdx.x;
  int wave = tid >> 6, lane = tid & 63;
  int wm = wave >> 1, wn = wave & 1;
  int quad = lane >> 4, l16 = lane & 15;
  int m0 = blockIdx.x * 128, n0 = blockIdx.y * 128;

  f32x4 acc[4][4];
#pragma unroll
  for (int mi = 0; mi < 4; mi++)
#pragma unroll
    for (int ni = 0; ni < 4; ni++) acc[mi][ni] = (f32x4){0.f, 0.f, 0.f, 0.f};

  // staging: each wave's gld16 covers 16 rows x 32 cols (1 KiB). 2 issues each for A,B.
  int rr = wave * 16 + (lane >> 2);   // row within 64-row half
  int sl = (lane & 3) * 8;            // ushort col offset (16B slot)
  const unsigned short* a0 = A + (size_t)(m0 + rr) * K + sl;
  const unsigned short* a1 = a0 + (size_t)64 * K;
  const unsigned short* b0 = Bt + (size_t)(n0 + rr) * K + sl;
  const unsigned short* b1 = b0 + (size_t)64 * K;
  unsigned short* lA0 = As + wave * 512;
  unsigned short* lA1 = As + 2048 + wave * 512;
  unsigned short* lB0 = Bs + wave * 512;
  unsigned short* lB1 = Bs + 2048 + wave * 512;

  for (int k0 = 0; k0 < K; k0 += 32) {
    gld16(a0 + k0, lA0);
    gld16(a1 + k0, lA1);
    gld16(b0 + k0, lB0);
    gld16(b1 + k0, lB1);
    __syncthreads();   // compiler emits vmcnt(0) drain before barrier
    bf16x8 af[4], bf[4];
#pragma unroll
    for (int i = 0; i < 4; i++) {
      af[i] = *(const bf16x8*)(&As[(wm * 64 + i * 16 + l16) * 32 + quad * 8]);
      bf[i] = *(const bf16x8*)(&Bs[(wn * 64 + i * 16 + l16) * 32 + quad * 8]);
    }
#pragma unroll
    for (int mi = 0; mi < 4; mi++)
#pragma unroll
      for (int ni = 0; ni < 4; ni++)
        acc[mi][ni] = __builtin_amdgcn_mfma_f32_16x16x32_bf16(af[mi], bf[ni],
                                                              acc[mi][ni], 0, 0, 0);
    __syncthreads();
  }
#pragma unroll
  for (int mi = 0; mi < 4; mi++)
#pragma unroll
    for (int ni = 0; ni < 4; ni++) {
      int row0 = m0 + wm * 64 + mi * 16 + quad * 4;
      int col = n0 + wn * 64 + ni * 16 + l16;
#pragma unroll
      for (int r = 0; r < 4; r++) {
        int row = row0 + r;
        if (row < M) C[(size_t)row * ldC + col] = f2b(acc[mi][ni][r]);
      }
    }
}

// ---------------- attention logits for group of 2 heads ----------------
__global__ __launch_bounds__(128) void elr_k(const unsigned short* __restrict__ feat,
                                             const unsigned short* __restrict__ al,
                                             const unsigned short* __restrict__ ar,
                                             float* __restrict__ el, float* __restrict__ er,
                                             int F, int GF) {
  int n = blockIdx.x;
  int wave = threadIdx.x >> 6, lane = threadIdx.x & 63;
  const unsigned short* fp = feat + (size_t)n * GF + wave * F;
  const unsigned short* alp = al + wave * F;
  const unsigned short* arp = ar + wave * F;
  float sl = 0.f, sr = 0.f;
  for (int f = lane; f < F; f += 64) {
    float fv = b2f(fp[f]);
    sl += fv * b2f(alp[f]);
    sr += fv * b2f(arp[f]);
  }
#pragma unroll
  for (int off = 32; off > 0; off >>= 1) {
    sl += __shfl_down(sl, off);
    sr += __shfl_down(sr, off);
  }
  if (lane == 0) { el[n * 2 + wave] = sl; er[n * 2 + wave] = sr; }
}

// ---------------- per-node softmax stats ----------------
__global__ __launch_bounds__(64) void stats_k(const int* __restrict__ indptr,
                                              const int* __restrict__ eidx,
                                              const int* __restrict__ src,
                                              const float* __restrict__ el,
                                              const float* __restrict__ er,
                                              float* __restrict__ emax,
                                              float* __restrict__ denom) {
  int n = blockIdx.x, lane = threadIdx.x;
  int beg = indptr[n], end = indptr[n + 1];
  int h = lane & 1, slot = lane >> 1;
  float ern = er[n * 2 + h];
  float m = -3.4e38f;
  for (int i = beg + slot; i < end; i += 32) {
    int s = src[eidx[i]];
    m = fmaxf(m, lrelu(el[s * 2 + h] + ern));
  }
#pragma unroll
  for (int off = 2; off < 64; off <<= 1) m = fmaxf(m, __shfl_xor(m, off));
  float sum = 0.f;
  for (int i = beg + slot; i < end; i += 32) {
    int s = src[eidx[i]];
    sum += __expf(lrelu(el[s * 2 + h] + ern) - m);
  }
#pragma unroll
  for (int off = 2; off < 64; off <<= 1) sum += __shfl_xor(sum, off);
  if (lane < 2) {
    emax[n * 2 + lane] = (end > beg) ? m : 0.f;
    denom[n * 2 + lane] = sum;
  }
}

// ---------------- CSR gather-aggregate for one group of 2 heads ----------------
__global__ __launch_bounds__(128) void agg_k(const unsigned short* __restrict__ feat,
                                             const float* __restrict__ el,
                                             const float* __restrict__ er,
                                             const float* __restrict__ emax,
                                             const float* __restrict__ denom,
                                             const int* __restrict__ indptr,
                                             const int* __restrict__ eidx,
                                             const int* __restrict__ src,
                                             const unsigned short* __restrict__ bias,
                                             void* __restrict__ outv,
                                             float* __restrict__ hacc,
                                             unsigned short* __restrict__ hout,
                                             int F, int GF, int mode, int g, int HFtot,
                                             const int* __restrict__ flag) {
  __shared__ float we[2], mxs[2], erns[2];
  __shared__ float sred[1024];
  int n = blockIdx.x, tid = threadIdx.x, nth = blockDim.x;
  if (tid < 2) {
    mxs[tid] = emax[n * 2 + tid];
    erns[tid] = er[n * 2 + tid];
  }
  int head = (tid * 8) / F;
  float racc[8];
#pragma unroll
  for (int q = 0; q < 8; q++) racc[q] = 0.f;
  __syncthreads();
  int beg = indptr[n], end = indptr[n + 1];
  for (int i = beg; i < end; i++) {
    int s = src[eidx[i]];
    if (tid < 2) {
      float v = lrelu(el[s * 2 + tid] + erns[tid]);
      we[tid] = __expf(v - mxs[tid]);
    }
    __syncthreads();
    U16B u; u.v = *(const uint4*)(feat + (size_t)s * GF + tid * 8);
    float w = we[head];
#pragma unroll
    for (int q = 0; q < 8; q++) racc[q] += w * b2f(u.s[q]);
    __syncthreads();
  }
  float dn = denom[n * 2 + head];
  float inv = dn > 0.f ? 1.f / dn : 0.f;
  if (mode == 1) {
    float vals[8];
#pragma unroll
    for (int q = 0; q < 8; q++) vals[q] = racc[q] * inv + b2f(bias[tid * 8 + q]);
    size_t base = (size_t)n * HFtot + (size_t)g * GF + tid * 8;
    if (*flag) {
      float* of = (float*)outv;
      *(float4*)(of + base)     = make_float4(vals[0], vals[1], vals[2], vals[3]);
      *(float4*)(of + base + 4) = make_float4(vals[4], vals[5], vals[6], vals[7]);
    } else {
      U16B u;
#pragma unroll
      for (int q = 0; q < 8; q++) u.s[q] = f2b(vals[q]);
      *(uint4*)((unsigned short*)outv + base) = u.v;
    }
  } else {
#pragma unroll
    for (int q = 0; q < 8; q++)
      sred[tid * 8 + q] = gelu_f(racc[q] * inv + b2f(bias[tid * 8 + q]));
    __syncthreads();
    for (int f = tid; f < F; f += nth) {
      float s2 = sred[f] + sred[F + f];
      size_t idx = (size_t)n * F + f;
      if (g == 3)      hout[idx] = f2b((hacc[idx] + s2) * 0.125f);
      else if (g == 0) hacc[idx] = s2;
      else             hacc[idx] += s2;
    }
  }
}

extern "C" void kernel_launch(void* const* d_in, const int* in_sizes, int n_in,
                              void* d_out, int out_size, void* d_ws, size_t ws_size,
                              hipStream_t stream) {
  const int* src = (const int*)d_in[1];
  const int* dst = (const int*)d_in[2];

  char* ws = (char*)d_ws;
  size_t off = 0;
  auto carve = [&](size_t bytes) -> void* {
    void* p = ws + off;
    off += (bytes + 255) & ~(size_t)255;
    return p;
  };
  // +128 padded rows on GEMM A-operands so 128-row staging never goes OOB
  unsigned short* feat = (unsigned short*)carve((size_t)NN * 1024 * 2);        // 41 MB
  float* hacc = (float*)carve((size_t)NN * 256 * 4);                           // 20.5 MB
  unsigned short* hbuf = (unsigned short*)carve((size_t)(NN + 128) * 256 * 2); // 10.3 MB
  unsigned short* nodeb = (unsigned short*)carve((size_t)(NN + 128) * 512 * 2);// 20.6 MB
  unsigned short* W1t = (unsigned short*)carve((size_t)2048 * 512 * 2);        // Bt [N][K]
  unsigned short* W2t = (unsigned short*)carve((size_t)2048 * 256 * 2);
  unsigned short* W3t = (unsigned short*)carve((size_t)4096 * 256 * 2);
  unsigned short* al1b = (unsigned short*)carve(2048 * 2);
  unsigned short* ar1b = (unsigned short*)carve(2048 * 2);
  unsigned short* b1b  = (unsigned short*)carve(2048 * 2);
  unsigned short* al2b = (unsigned short*)carve(2048 * 2);
  unsigned short* ar2b = (unsigned short*)carve(2048 * 2);
  unsigned short* b2b  = (unsigned short*)carve(2048 * 2);
  unsigned short* al3b = (unsigned short*)carve(4096 * 2);
  unsigned short* ar3b = (unsigned short*)carve(4096 * 2);
  unsigned short* b3b  = (unsigned short*)carve(4096 * 2);
  float* el = (float*)carve((size_t)NN * 2 * 4);
  float* er = (float*)carve((size_t)NN * 2 * 4);
  float* emax = (float*)carve((size_t)NN * 2 * 4);
  float* denom = (float*)carve((size_t)NN * 2 * 4);
  int* deg = (int*)carve((size_t)NN * 4);
  int* indptr = (int*)carve((size_t)(NN + 1) * 4);
  int* cursor = (int*)carve((size_t)NN * 4);
  int* eidx = (int*)carve((size_t)NE * 4);
  int* flag = (int*)carve(256);

  // dtype detect + normalize inputs to bf16 copies
  detect_k<<<1, 256, 0, stream>>>((const unsigned short*)d_in[3], flag);
  auto conv = [&](const void* s, unsigned short* d, int n) {
    conv_k<<<(n + 255) / 256, 256, 0, stream>>>(s, d, n, flag);
  };
  conv(d_in[0], nodeb, NN * 512);
  conv(d_in[4], al1b, 2048);  conv(d_in[5], ar1b, 2048);  conv(d_in[6], b1b, 2048);
  conv(d_in[8], al2b, 2048);  conv(d_in[9], ar2b, 2048);  conv(d_in[10], b2b, 2048);
  conv(d_in[12], al3b, 4096); conv(d_in[13], ar3b, 4096); conv(d_in[14], b3b, 4096);
  // weights: convert + transpose to Bt [N][K]
  convT_k<<<dim3(2048 / 32, 512 / 32), dim3(32, 8), 0, stream>>>(d_in[3], W1t, 512, 2048, flag);
  convT_k<<<dim3(2048 / 32, 256 / 32), dim3(32, 8), 0, stream>>>(d_in[7], W2t, 256, 2048, flag);
  convT_k<<<dim3(4096 / 32, 256 / 32), dim3(32, 8), 0, stream>>>(d_in[11], W3t, 256, 4096, flag);

  // CSR by dst
  hipMemsetAsync(deg, 0, (size_t)NN * 4, stream);
  hist_k<<<(NE + 255) / 256, 256, 0, stream>>>(dst, deg);
  scan_k<<<1, 1024, 0, stream>>>(deg, indptr, cursor);
  scatter_k<<<(NE + 255) / 256, 256, 0, stream>>>(dst, cursor, eidx);

  auto layer = [&](const unsigned short* A, int K, int F, const unsigned short* Wt,
                   const unsigned short* al, const unsigned short* ar,
                   const unsigned short* bb, int mode) {
    int GF = 2 * F;
    int HFtot = 8 * F;
    for (int g = 0; g < 4; g++) {
      dim3 gg((NN + 127) / 128, GF / 128);
      gemm_k<<<gg, 256, 0, stream>>>(A, Wt + (size_t)g * GF * K, feat, NN, K, GF);
      elr_k<<<NN, 128, 0, stream>>>(feat, al + (size_t)g * GF, ar + (size_t)g * GF, el, er, F, GF);
      stats_k<<<NN, 64, 0, stream>>>(indptr, eidx, src, el, er, emax, denom);
      agg_k<<<NN, GF / 8, 0, stream>>>(feat, el, er, emax, denom, indptr, eidx, src,
                                       bb + (size_t)g * GF, d_out, hacc, hbuf,
                                       F, GF, mode, g, HFtot, flag);
    }
  };

  layer(nodeb, 512, 256, W1t, al1b, ar1b, b1b, 0);
  layer(hbuf, 256, 256, W2t, al2b, ar2b, b2b, 0);
  layer(hbuf, 256, 512, W3t, al3b, ar3b, b3b, 1);
}

// Round 2
// 1485.261 us; speedup vs baseline: 1.0873x; 1.0873x over previous
//
#include <hip/hip_runtime.h>

#define NN 20000
#define NE 160000

typedef __bf16 bf16x8 __attribute__((ext_vector_type(8)));
typedef float f32x4 __attribute__((ext_vector_type(4)));

union U16B { uint4 v; unsigned short s[8]; };

__device__ __forceinline__ float b2f(unsigned short u) {
  return __uint_as_float(((unsigned int)u) << 16);
}
__device__ __forceinline__ unsigned short f2b(float f) {
  unsigned int x = __float_as_uint(f);
  x += 0x7fffu + ((x >> 16) & 1u);
  return (unsigned short)(x >> 16);
}
__device__ __forceinline__ float gelu_f(float v) {
  return 0.5f * v * (1.f + erff(v * 0.70710678118654752f));
}
__device__ __forceinline__ float lrelu(float v) { return v > 0.f ? v : 0.2f * v; }

// async global->LDS: 16B per lane, LDS dest = wave-uniform base + lane*16
typedef __attribute__((address_space(3))) unsigned char lds_uc;
typedef __attribute__((address_space(1))) const unsigned char glb_uc;
__device__ __forceinline__ void gld16(const void* g, void* l) {
  __builtin_amdgcn_global_load_lds((glb_uc*)g, (lds_uc*)l, 16, 0, 0);
}

// ---------------- input dtype detection ----------------
__global__ void detect_k(const unsigned short* __restrict__ w, int* __restrict__ flag) {
  __shared__ int bad;
  if (threadIdx.x == 0) bad = 0;
  __syncthreads();
  int cnt = 0;
  for (int i = threadIdx.x; i < 4096; i += 256) {
    unsigned int e = (w[i] >> 7) & 0xFFu;
    if (e < 100u || e > 154u) cnt++;
  }
  atomicAdd(&bad, cnt);
  __syncthreads();
  if (threadIdx.x == 0) *flag = (bad > 200) ? 1 : 0;   // 1 = inputs are fp32
}

// Normalize an input tensor to bf16 workspace copy.
__global__ void conv_k(const void* __restrict__ src, unsigned short* __restrict__ dst,
                       int n, const int* __restrict__ flag) {
  int i = blockIdx.x * blockDim.x + threadIdx.x;
  if (i >= n) return;
  if (*flag) dst[i] = f2b(((const float*)src)[i]);
  else       dst[i] = ((const unsigned short*)src)[i];
}

// Convert + transpose weight: src [K][C] (fp32 or bf16) -> dst [C][K] bf16.
__global__ __launch_bounds__(256) void convT_k(const void* __restrict__ src,
                                               unsigned short* __restrict__ dst,
                                               int K, int C, const int* __restrict__ flag) {
  __shared__ unsigned short t[32][33];
  int c0 = blockIdx.x * 32, k0 = blockIdx.y * 32;
  int x = threadIdx.x, y0 = threadIdx.y;   // blockDim (32, 8)
  int isf32 = *flag;
#pragma unroll
  for (int yy = y0; yy < 32; yy += 8) {
    size_t idx = (size_t)(k0 + yy) * C + (c0 + x);
    unsigned short v;
    if (isf32) v = f2b(((const float*)src)[idx]);
    else       v = ((const unsigned short*)src)[idx];
    t[yy][x] = v;
  }
  __syncthreads();
#pragma unroll
  for (int yy = y0; yy < 32; yy += 8) {
    dst[(size_t)(c0 + yy) * K + (k0 + x)] = t[x][yy];
  }
}

// ---------------- CSR build (dst-sorted) ----------------
__global__ void hist_k(const int* __restrict__ dst, int* __restrict__ deg) {
  int e = blockIdx.x * blockDim.x + threadIdx.x;
  if (e < NE) atomicAdd(&deg[dst[e]], 1);
}

__global__ __launch_bounds__(1024) void scan_k(const int* __restrict__ deg,
                                               int* __restrict__ indptr,
                                               int* __restrict__ cursor) {
  __shared__ int buf[1024];
  __shared__ int carryS;
  int tid = threadIdx.x;
  if (tid == 0) { carryS = 0; indptr[0] = 0; }
  __syncthreads();
  for (int base = 0; base < NN; base += 1024) {
    int i = base + tid;
    int v = (i < NN) ? deg[i] : 0;
    buf[tid] = v;
    __syncthreads();
    for (int off = 1; off < 1024; off <<= 1) {
      int t = (tid >= off) ? buf[tid - off] : 0;
      __syncthreads();
      buf[tid] += t;
      __syncthreads();
    }
    int c = carryS;
    if (i < NN) {
      indptr[i + 1] = c + buf[tid];
      cursor[i] = c + buf[tid] - v;   // exclusive
    }
    __syncthreads();
    if (tid == 0) carryS = c + buf[1023];
    __syncthreads();
  }
}

// store CSR-ordered SOURCE ids directly (one less indirection downstream)
__global__ void scatter_k(const int* __restrict__ src, const int* __restrict__ dst,
                          int* __restrict__ cursor, int* __restrict__ srcC) {
  int e = blockIdx.x * blockDim.x + threadIdx.x;
  if (e < NE) {
    int p = atomicAdd(&cursor[dst[e]], 1);
    srcC[p] = src[e];
  }
}

// ---------------- bf16 MFMA GEMM (m97 structure: 128x128x32, global_load_lds) ----
__global__ __launch_bounds__(256) void gemm_k(const unsigned short* __restrict__ A,
                                              const unsigned short* __restrict__ Bt,
                                              unsigned short* __restrict__ C,
                                              int M, int K, int ldC) {
  __shared__ unsigned short As[128 * 32];
  __shared__ unsigned short Bs[128 * 32];
  int tid = threadIdx.x;
  int wave = tid >> 6, lane = tid & 63;
  int wm = wave >> 1, wn = wave & 1;
  int quad = lane >> 4, l16 = lane & 15;
  int m0 = blockIdx.x * 128, n0 = blockIdx.y * 128;

  f32x4 acc[4][4];
#pragma unroll
  for (int mi = 0; mi < 4; mi++)
#pragma unroll
    for (int ni = 0; ni < 4; ni++) acc[mi][ni] = (f32x4){0.f, 0.f, 0.f, 0.f};

  int rr = wave * 16 + (lane >> 2);
  int sl = (lane & 3) * 8;
  const unsigned short* a0 = A + (size_t)(m0 + rr) * K + sl;
  const unsigned short* a1 = a0 + (size_t)64 * K;
  const unsigned short* b0 = Bt + (size_t)(n0 + rr) * K + sl;
  const unsigned short* b1 = b0 + (size_t)64 * K;
  unsigned short* lA0 = As + wave * 512;
  unsigned short* lA1 = As + 2048 + wave * 512;
  unsigned short* lB0 = Bs + wave * 512;
  unsigned short* lB1 = Bs + 2048 + wave * 512;

  for (int k0 = 0; k0 < K; k0 += 32) {
    gld16(a0 + k0, lA0);
    gld16(a1 + k0, lA1);
    gld16(b0 + k0, lB0);
    gld16(b1 + k0, lB1);
    __syncthreads();
    bf16x8 af[4], bf[4];
#pragma unroll
    for (int i = 0; i < 4; i++) {
      af[i] = *(const bf16x8*)(&As[(wm * 64 + i * 16 + l16) * 32 + quad * 8]);
      bf[i] = *(const bf16x8*)(&Bs[(wn * 64 + i * 16 + l16) * 32 + quad * 8]);
    }
#pragma unroll
    for (int mi = 0; mi < 4; mi++)
#pragma unroll
      for (int ni = 0; ni < 4; ni++)
        acc[mi][ni] = __builtin_amdgcn_mfma_f32_16x16x32_bf16(af[mi], bf[ni],
                                                              acc[mi][ni], 0, 0, 0);
    __syncthreads();
  }
#pragma unroll
  for (int mi = 0; mi < 4; mi++)
#pragma unroll
    for (int ni = 0; ni < 4; ni++) {
      int row0 = m0 + wm * 64 + mi * 16 + quad * 4;
      int col = n0 + wn * 64 + ni * 16 + l16;
#pragma unroll
      for (int r = 0; r < 4; r++) {
        int row = row0 + r;
        if (row < M) C[(size_t)row * ldC + col] = f2b(acc[mi][ni][r]);
      }
    }
}

// ---------------- attention logits for group of 2 heads ----------------
__global__ __launch_bounds__(128) void elr_k(const unsigned short* __restrict__ feat,
                                             const unsigned short* __restrict__ al,
                                             const unsigned short* __restrict__ ar,
                                             float* __restrict__ el, float* __restrict__ er,
                                             int F, int GF) {
  int n = blockIdx.x;
  int wave = threadIdx.x >> 6, lane = threadIdx.x & 63;
  const unsigned short* fp = feat + (size_t)n * GF + wave * F;
  const unsigned short* alp = al + wave * F;
  const unsigned short* arp = ar + wave * F;
  float sl = 0.f, sr = 0.f;
  for (int f = lane; f < F; f += 64) {
    float fv = b2f(fp[f]);
    sl += fv * b2f(alp[f]);
    sr += fv * b2f(arp[f]);
  }
#pragma unroll
  for (int off = 32; off > 0; off >>= 1) {
    sl += __shfl_down(sl, off);
    sr += __shfl_down(sr, off);
  }
  if (lane == 0) { el[n * 2 + wave] = sl; er[n * 2 + wave] = sr; }
}

// ---------------- per-node softmax stats + per-edge alpha (CSR order) ----------
__global__ __launch_bounds__(64) void stats2_k(const int* __restrict__ indptr,
                                               const int* __restrict__ srcC,
                                               const float* __restrict__ el,
                                               const float* __restrict__ er,
                                               float* __restrict__ alpha2) {
  int n = blockIdx.x, lane = threadIdx.x;
  int beg = indptr[n], end = indptr[n + 1];
  int h = lane & 1, slot = lane >> 1;
  float ern = er[n * 2 + h];
  float m = -3.4e38f;
  for (int i = beg + slot; i < end; i += 32) {
    int s = srcC[i];
    m = fmaxf(m, lrelu(el[s * 2 + h] + ern));
  }
#pragma unroll
  for (int off = 2; off < 64; off <<= 1) m = fmaxf(m, __shfl_xor(m, off));
  float sum = 0.f;
  for (int i = beg + slot; i < end; i += 32) {
    int s = srcC[i];
    sum += __expf(lrelu(el[s * 2 + h] + ern) - m);
  }
#pragma unroll
  for (int off = 2; off < 64; off <<= 1) sum += __shfl_xor(sum, off);
  float inv = sum > 0.f ? 1.f / sum : 0.f;
  for (int i = beg + slot; i < end; i += 32) {
    int s = srcC[i];
    float v = lrelu(el[s * 2 + h] + ern);
    alpha2[(size_t)i * 2 + h] = __expf(v - m) * inv;
  }
}

// ---------------- CSR gather-aggregate for one group of 2 heads ----------------
// barrier-free inner loop: weights come precomputed from alpha2 (CSR-ordered)
__global__ __launch_bounds__(128) void agg_k(const unsigned short* __restrict__ feat,
                                             const float* __restrict__ alpha2,
                                             const int* __restrict__ indptr,
                                             const int* __restrict__ srcC,
                                             const unsigned short* __restrict__ bias,
                                             void* __restrict__ outv,
                                             float* __restrict__ hacc,
                                             unsigned short* __restrict__ hout,
                                             int F, int GF, int mode, int g, int HFtot,
                                             const int* __restrict__ flag) {
  __shared__ float sred[1024];
  int n = blockIdx.x, tid = threadIdx.x, nth = blockDim.x;
  int head = (tid * 8) / F;
  float racc[8];
#pragma unroll
  for (int q = 0; q < 8; q++) racc[q] = 0.f;
  int beg = indptr[n], end = indptr[n + 1];
  int i = beg;
  for (; i + 1 < end; i += 2) {
    int s0 = srcC[i], s1 = srcC[i + 1];
    float2 a0 = *(const float2*)(alpha2 + (size_t)i * 2);
    float2 a1 = *(const float2*)(alpha2 + (size_t)i * 2 + 2);
    float w0 = head ? a0.y : a0.x;
    float w1 = head ? a1.y : a1.x;
    U16B u0, u1;
    u0.v = *(const uint4*)(feat + (size_t)s0 * GF + tid * 8);
    u1.v = *(const uint4*)(feat + (size_t)s1 * GF + tid * 8);
#pragma unroll
    for (int q = 0; q < 8; q++)
      racc[q] += w0 * b2f(u0.s[q]) + w1 * b2f(u1.s[q]);
  }
  if (i < end) {
    int s0 = srcC[i];
    float2 a0 = *(const float2*)(alpha2 + (size_t)i * 2);
    float w0 = head ? a0.y : a0.x;
    U16B u0;
    u0.v = *(const uint4*)(feat + (size_t)s0 * GF + tid * 8);
#pragma unroll
    for (int q = 0; q < 8; q++) racc[q] += w0 * b2f(u0.s[q]);
  }
  if (mode == 1) {
    float vals[8];
#pragma unroll
    for (int q = 0; q < 8; q++) vals[q] = racc[q] + b2f(bias[tid * 8 + q]);
    size_t base = (size_t)n * HFtot + (size_t)g * GF + tid * 8;
    if (*flag) {
      float* of = (float*)outv;
      *(float4*)(of + base)     = make_float4(vals[0], vals[1], vals[2], vals[3]);
      *(float4*)(of + base + 4) = make_float4(vals[4], vals[5], vals[6], vals[7]);
    } else {
      U16B u;
#pragma unroll
      for (int q = 0; q < 8; q++) u.s[q] = f2b(vals[q]);
      *(uint4*)((unsigned short*)outv + base) = u.v;
    }
  } else {
#pragma unroll
    for (int q = 0; q < 8; q++)
      sred[tid * 8 + q] = gelu_f(racc[q] + b2f(bias[tid * 8 + q]));
    __syncthreads();
    for (int f = tid; f < F; f += nth) {
      float s2 = sred[f] + sred[F + f];
      size_t idx = (size_t)n * F + f;
      if (g == 3)      hout[idx] = f2b((hacc[idx] + s2) * 0.125f);
      else if (g == 0) hacc[idx] = s2;
      else             hacc[idx] += s2;
    }
  }
}

extern "C" void kernel_launch(void* const* d_in, const int* in_sizes, int n_in,
                              void* d_out, int out_size, void* d_ws, size_t ws_size,
                              hipStream_t stream) {
  const int* src = (const int*)d_in[1];
  const int* dst = (const int*)d_in[2];

  char* ws = (char*)d_ws;
  size_t off = 0;
  auto carve = [&](size_t bytes) -> void* {
    void* p = ws + off;
    off += (bytes + 255) & ~(size_t)255;
    return p;
  };
  unsigned short* feat = (unsigned short*)carve((size_t)NN * 1024 * 2);        // 41 MB
  float* hacc = (float*)carve((size_t)NN * 256 * 4);                           // 20.5 MB
  unsigned short* hbuf = (unsigned short*)carve((size_t)(NN + 128) * 256 * 2); // 10.3 MB
  unsigned short* nodeb = (unsigned short*)carve((size_t)(NN + 128) * 512 * 2);// 20.6 MB
  unsigned short* W1t = (unsigned short*)carve((size_t)2048 * 512 * 2);        // Bt [N][K]
  unsigned short* W2t = (unsigned short*)carve((size_t)2048 * 256 * 2);
  unsigned short* W3t = (unsigned short*)carve((size_t)4096 * 256 * 2);
  unsigned short* al1b = (unsigned short*)carve(2048 * 2);
  unsigned short* ar1b = (unsigned short*)carve(2048 * 2);
  unsigned short* b1b  = (unsigned short*)carve(2048 * 2);
  unsigned short* al2b = (unsigned short*)carve(2048 * 2);
  unsigned short* ar2b = (unsigned short*)carve(2048 * 2);
  unsigned short* b2b  = (unsigned short*)carve(2048 * 2);
  unsigned short* al3b = (unsigned short*)carve(4096 * 2);
  unsigned short* ar3b = (unsigned short*)carve(4096 * 2);
  unsigned short* b3b  = (unsigned short*)carve(4096 * 2);
  float* el = (float*)carve((size_t)NN * 2 * 4);
  float* er = (float*)carve((size_t)NN * 2 * 4);
  float* alpha2 = (float*)carve((size_t)NE * 2 * 4);                           // 1.28 MB
  int* deg = (int*)carve((size_t)NN * 4);
  int* indptr = (int*)carve((size_t)(NN + 1) * 4);
  int* cursor = (int*)carve((size_t)NN * 4);
  int* srcC = (int*)carve((size_t)NE * 4);
  int* flag = (int*)carve(256);

  // dtype detect + normalize inputs to bf16 copies
  detect_k<<<1, 256, 0, stream>>>((const unsigned short*)d_in[3], flag);
  auto conv = [&](const void* s, unsigned short* d, int n) {
    conv_k<<<(n + 255) / 256, 256, 0, stream>>>(s, d, n, flag);
  };
  conv(d_in[0], nodeb, NN * 512);
  conv(d_in[4], al1b, 2048);  conv(d_in[5], ar1b, 2048);  conv(d_in[6], b1b, 2048);
  conv(d_in[8], al2b, 2048);  conv(d_in[9], ar2b, 2048);  conv(d_in[10], b2b, 2048);
  conv(d_in[12], al3b, 4096); conv(d_in[13], ar3b, 4096); conv(d_in[14], b3b, 4096);
  // weights: convert + transpose to Bt [N][K]
  convT_k<<<dim3(2048 / 32, 512 / 32), dim3(32, 8), 0, stream>>>(d_in[3], W1t, 512, 2048, flag);
  convT_k<<<dim3(2048 / 32, 256 / 32), dim3(32, 8), 0, stream>>>(d_in[7], W2t, 256, 2048, flag);
  convT_k<<<dim3(4096 / 32, 256 / 32), dim3(32, 8), 0, stream>>>(d_in[11], W3t, 256, 4096, flag);

  // CSR by dst
  hipMemsetAsync(deg, 0, (size_t)NN * 4, stream);
  hist_k<<<(NE + 255) / 256, 256, 0, stream>>>(dst, deg);
  scan_k<<<1, 1024, 0, stream>>>(deg, indptr, cursor);
  scatter_k<<<(NE + 255) / 256, 256, 0, stream>>>(src, dst, cursor, srcC);

  auto layer = [&](const unsigned short* A, int K, int F, const unsigned short* Wt,
                   const unsigned short* al, const unsigned short* ar,
                   const unsigned short* bb, int mode) {
    int GF = 2 * F;
    int HFtot = 8 * F;
    for (int g = 0; g < 4; g++) {
      dim3 gg((NN + 127) / 128, GF / 128);
      gemm_k<<<gg, 256, 0, stream>>>(A, Wt + (size_t)g * GF * K, feat, NN, K, GF);
      elr_k<<<NN, 128, 0, stream>>>(feat, al + (size_t)g * GF, ar + (size_t)g * GF, el, er, F, GF);
      stats2_k<<<NN, 64, 0, stream>>>(indptr, srcC, el, er, alpha2);
      agg_k<<<NN, GF / 8, 0, stream>>>(feat, alpha2, indptr, srcC,
                                       bb + (size_t)g * GF, d_out, hacc, hbuf,
                                       F, GF, mode, g, HFtot, flag);
    }
  };

  layer(nodeb, 512, 256, W1t, al1b, ar1b, b1b, 0);
  layer(hbuf, 256, 256, W2t, al2b, ar2b, b2b, 0);
  layer(hbuf, 256, 512, W3t, al3b, ar3b, b3b, 1);
}

// Round 3
// 1152.689 us; speedup vs baseline: 1.4010x; 1.2885x over previous
//
#include <hip/hip_runtime.h>

#define NN 20000
#define NE 160000

typedef __bf16 bf16x8 __attribute__((ext_vector_type(8)));
typedef float f32x4 __attribute__((ext_vector_type(4)));

union U16B { uint4 v; unsigned short s[8]; };

__device__ __forceinline__ float b2f(unsigned short u) {
  return __uint_as_float(((unsigned int)u) << 16);
}
__device__ __forceinline__ unsigned short f2b(float f) {
  unsigned int x = __float_as_uint(f);
  x += 0x7fffu + ((x >> 16) & 1u);
  return (unsigned short)(x >> 16);
}
__device__ __forceinline__ float gelu_f(float v) {
  return 0.5f * v * (1.f + erff(v * 0.70710678118654752f));
}
__device__ __forceinline__ float lrelu(float v) { return v > 0.f ? v : 0.2f * v; }

// async global->LDS: 16B per lane, LDS dest = wave-uniform base + lane*16
typedef __attribute__((address_space(3))) unsigned char lds_uc;
typedef __attribute__((address_space(1))) const unsigned char glb_uc;
__device__ __forceinline__ void gld16(const void* g, void* l) {
  __builtin_amdgcn_global_load_lds((glb_uc*)g, (lds_uc*)l, 16, 0, 0);
}

// ---------------- input dtype detection ----------------
__global__ void detect_k(const unsigned short* __restrict__ w, int* __restrict__ flag) {
  __shared__ int bad;
  if (threadIdx.x == 0) bad = 0;
  __syncthreads();
  int cnt = 0;
  for (int i = threadIdx.x; i < 4096; i += 256) {
    unsigned int e = (w[i] >> 7) & 0xFFu;
    if (e < 100u || e > 154u) cnt++;
  }
  atomicAdd(&bad, cnt);
  __syncthreads();
  if (threadIdx.x == 0) *flag = (bad > 200) ? 1 : 0;   // 1 = inputs are fp32
}

// Normalize an input tensor to bf16 workspace copy.
__global__ void conv_k(const void* __restrict__ src, unsigned short* __restrict__ dst,
                       int n, const int* __restrict__ flag) {
  int i = blockIdx.x * blockDim.x + threadIdx.x;
  if (i >= n) return;
  if (*flag) dst[i] = f2b(((const float*)src)[i]);
  else       dst[i] = ((const unsigned short*)src)[i];
}

// Convert + transpose weight: src [K][C] (fp32 or bf16) -> dst [C][K] bf16.
__global__ __launch_bounds__(256) void convT_k(const void* __restrict__ src,
                                               unsigned short* __restrict__ dst,
                                               int K, int C, const int* __restrict__ flag) {
  __shared__ unsigned short t[32][33];
  int c0 = blockIdx.x * 32, k0 = blockIdx.y * 32;
  int x = threadIdx.x, y0 = threadIdx.y;   // blockDim (32, 8)
  int isf32 = *flag;
#pragma unroll
  for (int yy = y0; yy < 32; yy += 8) {
    size_t idx = (size_t)(k0 + yy) * C + (c0 + x);
    unsigned short v;
    if (isf32) v = f2b(((const float*)src)[idx]);
    else       v = ((const unsigned short*)src)[idx];
    t[yy][x] = v;
  }
  __syncthreads();
#pragma unroll
  for (int yy = y0; yy < 32; yy += 8) {
    dst[(size_t)(c0 + yy) * K + (k0 + x)] = t[x][yy];
  }
}

// ---------------- CSR build (dst-sorted) ----------------
__global__ void hist_k(const int* __restrict__ dst, int* __restrict__ deg) {
  int e = blockIdx.x * blockDim.x + threadIdx.x;
  if (e < NE) atomicAdd(&deg[dst[e]], 1);
}

__global__ __launch_bounds__(1024) void scan_k(const int* __restrict__ deg,
                                               int* __restrict__ indptr,
                                               int* __restrict__ cursor) {
  __shared__ int buf[1024];
  __shared__ int carryS;
  int tid = threadIdx.x;
  if (tid == 0) { carryS = 0; indptr[0] = 0; }
  __syncthreads();
  for (int base = 0; base < NN; base += 1024) {
    int i = base + tid;
    int v = (i < NN) ? deg[i] : 0;
    buf[tid] = v;
    __syncthreads();
    for (int off = 1; off < 1024; off <<= 1) {
      int t = (tid >= off) ? buf[tid - off] : 0;
      __syncthreads();
      buf[tid] += t;
      __syncthreads();
    }
    int c = carryS;
    if (i < NN) {
      indptr[i + 1] = c + buf[tid];
      cursor[i] = c + buf[tid] - v;   // exclusive
    }
    __syncthreads();
    if (tid == 0) carryS = c + buf[1023];
    __syncthreads();
  }
}

// store CSR-ordered SOURCE ids directly
__global__ void scatter_k(const int* __restrict__ src, const int* __restrict__ dst,
                          int* __restrict__ cursor, int* __restrict__ srcC) {
  int e = blockIdx.x * blockDim.x + threadIdx.x;
  if (e < NE) {
    int p = atomicAdd(&cursor[dst[e]], 1);
    srcC[p] = src[e];
  }
}

// ---------------- bf16 MFMA GEMM (m97 structure: 128x128x32, global_load_lds) ----
__global__ __launch_bounds__(256) void gemm_k(const unsigned short* __restrict__ A,
                                              const unsigned short* __restrict__ Bt,
                                              unsigned short* __restrict__ C,
                                              int M, int K, int ldC) {
  __shared__ unsigned short As[128 * 32];
  __shared__ unsigned short Bs[128 * 32];
  int tid = threadIdx.x;
  int wave = tid >> 6, lane = tid & 63;
  int wm = wave >> 1, wn = wave & 1;
  int quad = lane >> 4, l16 = lane & 15;
  int m0 = blockIdx.x * 128, n0 = blockIdx.y * 128;

  f32x4 acc[4][4];
#pragma unroll
  for (int mi = 0; mi < 4; mi++)
#pragma unroll
    for (int ni = 0; ni < 4; ni++) acc[mi][ni] = (f32x4){0.f, 0.f, 0.f, 0.f};

  int rr = wave * 16 + (lane >> 2);
  int sl = (lane & 3) * 8;
  const unsigned short* a0 = A + (size_t)(m0 + rr) * K + sl;
  const unsigned short* a1 = a0 + (size_t)64 * K;
  const unsigned short* b0 = Bt + (size_t)(n0 + rr) * K + sl;
  const unsigned short* b1 = b0 + (size_t)64 * K;
  unsigned short* lA0 = As + wave * 512;
  unsigned short* lA1 = As + 2048 + wave * 512;
  unsigned short* lB0 = Bs + wave * 512;
  unsigned short* lB1 = Bs + 2048 + wave * 512;

  for (int k0 = 0; k0 < K; k0 += 32) {
    gld16(a0 + k0, lA0);
    gld16(a1 + k0, lA1);
    gld16(b0 + k0, lB0);
    gld16(b1 + k0, lB1);
    __syncthreads();
    bf16x8 af[4], bf[4];
#pragma unroll
    for (int i = 0; i < 4; i++) {
      af[i] = *(const bf16x8*)(&As[(wm * 64 + i * 16 + l16) * 32 + quad * 8]);
      bf[i] = *(const bf16x8*)(&Bs[(wn * 64 + i * 16 + l16) * 32 + quad * 8]);
    }
#pragma unroll
    for (int mi = 0; mi < 4; mi++)
#pragma unroll
      for (int ni = 0; ni < 4; ni++)
        acc[mi][ni] = __builtin_amdgcn_mfma_f32_16x16x32_bf16(af[mi], bf[ni],
                                                              acc[mi][ni], 0, 0, 0);
    __syncthreads();
  }
#pragma unroll
  for (int mi = 0; mi < 4; mi++)
#pragma unroll
    for (int ni = 0; ni < 4; ni++) {
      int row0 = m0 + wm * 64 + mi * 16 + quad * 4;
      int col = n0 + wn * 64 + ni * 16 + l16;
#pragma unroll
      for (int r = 0; r < 4; r++) {
        int row = row0 + r;
        if (row < M) C[(size_t)row * ldC + col] = f2b(acc[mi][ni][r]);
      }
    }
}

// ---------------- attention logits, all 8 heads ----------------
// threads = HF/8; group of G=F/8 threads per head (G=32 or 64, lgG=5 or 6)
__global__ __launch_bounds__(512) void elr8_k(const unsigned short* __restrict__ feat,
                                              const unsigned short* __restrict__ al,
                                              const unsigned short* __restrict__ ar,
                                              float* __restrict__ el8, float* __restrict__ er8,
                                              int F, int HF, int lgG) {
  int n = blockIdx.x, tid = threadIdx.x;
  int G = 1 << lgG;
  int head = tid >> lgG;
  int off = (tid & (G - 1)) << 3;
  U16B uf, ua, ub;
  uf.v = *(const uint4*)(feat + (size_t)n * HF + head * F + off);
  ua.v = *(const uint4*)(al + head * F + off);
  ub.v = *(const uint4*)(ar + head * F + off);
  float sl = 0.f, sr = 0.f;
#pragma unroll
  for (int q = 0; q < 8; q++) {
    float fv = b2f(uf.s[q]);
    sl += fv * b2f(ua.s[q]);
    sr += fv * b2f(ub.s[q]);
  }
  for (int o = G >> 1; o > 0; o >>= 1) {
    sl += __shfl_down(sl, o);
    sr += __shfl_down(sr, o);
  }
  if ((tid & (G - 1)) == 0) {
    el8[n * 8 + head] = sl;
    er8[n * 8 + head] = sr;
  }
}

// ---------------- per-node softmax stats + normalized alpha, all 8 heads ------
// 64 threads = 8 edge-slots x 8 heads
__global__ __launch_bounds__(64) void stats8_k(const int* __restrict__ indptr,
                                               const int* __restrict__ srcC,
                                               const float* __restrict__ el8,
                                               const float* __restrict__ er8,
                                               float* __restrict__ alpha8) {
  int n = blockIdx.x, lane = threadIdx.x;
  int beg = indptr[n], end = indptr[n + 1];
  int h = lane & 7, slot = lane >> 3;
  float ern = er8[n * 8 + h];
  float m = -3.4e38f;
  for (int i = beg + slot; i < end; i += 8) {
    int s = srcC[i];
    m = fmaxf(m, lrelu(el8[s * 8 + h] + ern));
  }
#pragma unroll
  for (int o = 8; o < 64; o <<= 1) m = fmaxf(m, __shfl_xor(m, o));
  float sum = 0.f;
  for (int i = beg + slot; i < end; i += 8) {
    int s = srcC[i];
    sum += __expf(lrelu(el8[s * 8 + h] + ern) - m);
  }
#pragma unroll
  for (int o = 8; o < 64; o <<= 1) sum += __shfl_xor(sum, o);
  float inv = sum > 0.f ? 1.f / sum : 0.f;
  for (int i = beg + slot; i < end; i += 8) {
    int s = srcC[i];
    float v = lrelu(el8[s * 8 + h] + ern);
    alpha8[(size_t)i * 8 + h] = __expf(v - m) * inv;
  }
}

// ---------------- CSR gather-aggregate, all 8 heads in one pass ----------------
// threads = HF/8 (256 or 512); head = tid>>lgG; barrier-free edge loop.
// mode 0: gelu + head-mean in-kernel -> hout bf16 [NN][F]
// mode 1: final output (+bias), f32 or bf16 by flag
__global__ __launch_bounds__(512) void agg8_k(const unsigned short* __restrict__ feat,
                                              const float* __restrict__ alpha8,
                                              const int* __restrict__ indptr,
                                              const int* __restrict__ srcC,
                                              const unsigned short* __restrict__ bias,
                                              void* __restrict__ outv,
                                              unsigned short* __restrict__ hout,
                                              int F, int HF, int lgG, int mode,
                                              const int* __restrict__ flag) {
  __shared__ float sred[2048];
  int n = blockIdx.x, tid = threadIdx.x;
  int head = tid >> lgG;
  float racc[8];
#pragma unroll
  for (int q = 0; q < 8; q++) racc[q] = 0.f;
  int beg = indptr[n], end = indptr[n + 1];
  int i = beg;
  for (; i + 1 < end; i += 2) {
    int s0 = srcC[i], s1 = srcC[i + 1];
    float w0 = alpha8[(size_t)i * 8 + head];
    float w1 = alpha8[(size_t)(i + 1) * 8 + head];
    U16B u0, u1;
    u0.v = *(const uint4*)(feat + (size_t)s0 * HF + tid * 8);
    u1.v = *(const uint4*)(feat + (size_t)s1 * HF + tid * 8);
#pragma unroll
    for (int q = 0; q < 8; q++)
      racc[q] += w0 * b2f(u0.s[q]) + w1 * b2f(u1.s[q]);
  }
  if (i < end) {
    int s0 = srcC[i];
    float w0 = alpha8[(size_t)i * 8 + head];
    U16B u0;
    u0.v = *(const uint4*)(feat + (size_t)s0 * HF + tid * 8);
#pragma unroll
    for (int q = 0; q < 8; q++) racc[q] += w0 * b2f(u0.s[q]);
  }
  if (mode == 1) {
    float vals[8];
#pragma unroll
    for (int q = 0; q < 8; q++) vals[q] = racc[q] + b2f(bias[tid * 8 + q]);
    size_t base = (size_t)n * HF + tid * 8;
    if (*flag) {
      float* of = (float*)outv;
      *(float4*)(of + base)     = make_float4(vals[0], vals[1], vals[2], vals[3]);
      *(float4*)(of + base + 4) = make_float4(vals[4], vals[5], vals[6], vals[7]);
    } else {
      U16B u;
#pragma unroll
      for (int q = 0; q < 8; q++) u.s[q] = f2b(vals[q]);
      *(uint4*)((unsigned short*)outv + base) = u.v;
    }
  } else {
#pragma unroll
    for (int q = 0; q < 8; q++)
      sred[tid * 8 + q] = gelu_f(racc[q] + b2f(bias[tid * 8 + q]));
    __syncthreads();
    // head-mean: threads == HF/8 == 8F/8 == F for mode-0 layers (F=256)
    if (tid < F) {
      float s = 0.f;
#pragma unroll
      for (int h = 0; h < 8; h++) s += sred[h * F + tid];
      hout[(size_t)n * F + tid] = f2b(s * 0.125f);
    }
  }
}

extern "C" void kernel_launch(void* const* d_in, const int* in_sizes, int n_in,
                              void* d_out, int out_size, void* d_ws, size_t ws_size,
                              hipStream_t stream) {
  const int* src = (const int*)d_in[1];
  const int* dst = (const int*)d_in[2];

  char* ws = (char*)d_ws;
  size_t off = 0;
  auto carve = [&](size_t bytes) -> void* {
    void* p = ws + off;
    off += (bytes + 255) & ~(size_t)255;
    return p;
  };
  unsigned short* feat = (unsigned short*)carve((size_t)NN * 4096 * 2);        // 164 MB
  unsigned short* hbuf = (unsigned short*)carve((size_t)(NN + 128) * 256 * 2); // 10.3 MB
  unsigned short* nodeb = (unsigned short*)carve((size_t)(NN + 128) * 512 * 2);// 20.6 MB
  unsigned short* W1t = (unsigned short*)carve((size_t)2048 * 512 * 2);        // Bt [N][K]
  unsigned short* W2t = (unsigned short*)carve((size_t)2048 * 256 * 2);
  unsigned short* W3t = (unsigned short*)carve((size_t)4096 * 256 * 2);
  unsigned short* al1b = (unsigned short*)carve(2048 * 2);
  unsigned short* ar1b = (unsigned short*)carve(2048 * 2);
  unsigned short* b1b  = (unsigned short*)carve(2048 * 2);
  unsigned short* al2b = (unsigned short*)carve(2048 * 2);
  unsigned short* ar2b = (unsigned short*)carve(2048 * 2);
  unsigned short* b2b  = (unsigned short*)carve(2048 * 2);
  unsigned short* al3b = (unsigned short*)carve(4096 * 2);
  unsigned short* ar3b = (unsigned short*)carve(4096 * 2);
  unsigned short* b3b  = (unsigned short*)carve(4096 * 2);
  float* el8 = (float*)carve((size_t)NN * 8 * 4);
  float* er8 = (float*)carve((size_t)NN * 8 * 4);
  float* alpha8 = (float*)carve((size_t)NE * 8 * 4);                           // 5.1 MB
  int* deg = (int*)carve((size_t)NN * 4);
  int* indptr = (int*)carve((size_t)(NN + 1) * 4);
  int* cursor = (int*)carve((size_t)NN * 4);
  int* srcC = (int*)carve((size_t)NE * 4);
  int* flag = (int*)carve(256);

  // dtype detect + normalize inputs to bf16 copies
  detect_k<<<1, 256, 0, stream>>>((const unsigned short*)d_in[3], flag);
  auto conv = [&](const void* s, unsigned short* d, int n) {
    conv_k<<<(n + 255) / 256, 256, 0, stream>>>(s, d, n, flag);
  };
  conv(d_in[0], nodeb, NN * 512);
  conv(d_in[4], al1b, 2048);  conv(d_in[5], ar1b, 2048);  conv(d_in[6], b1b, 2048);
  conv(d_in[8], al2b, 2048);  conv(d_in[9], ar2b, 2048);  conv(d_in[10], b2b, 2048);
  conv(d_in[12], al3b, 4096); conv(d_in[13], ar3b, 4096); conv(d_in[14], b3b, 4096);
  // weights: convert + transpose to Bt [N][K]
  convT_k<<<dim3(2048 / 32, 512 / 32), dim3(32, 8), 0, stream>>>(d_in[3], W1t, 512, 2048, flag);
  convT_k<<<dim3(2048 / 32, 256 / 32), dim3(32, 8), 0, stream>>>(d_in[7], W2t, 256, 2048, flag);
  convT_k<<<dim3(4096 / 32, 256 / 32), dim3(32, 8), 0, stream>>>(d_in[11], W3t, 256, 4096, flag);

  // CSR by dst
  hipMemsetAsync(deg, 0, (size_t)NN * 4, stream);
  hist_k<<<(NE + 255) / 256, 256, 0, stream>>>(dst, deg);
  scan_k<<<1, 1024, 0, stream>>>(deg, indptr, cursor);
  scatter_k<<<(NE + 255) / 256, 256, 0, stream>>>(src, dst, cursor, srcC);

  auto layer = [&](const unsigned short* A, int K, int F, const unsigned short* Wt,
                   const unsigned short* al, const unsigned short* ar,
                   const unsigned short* bb, int mode) {
    int HF = 8 * F;
    int lgG = (F == 256) ? 5 : 6;   // G = F/8
    int th = HF / 8;                // 256 or 512
    dim3 gg((NN + 127) / 128, HF / 128);
    gemm_k<<<gg, 256, 0, stream>>>(A, Wt, feat, NN, K, HF);
    elr8_k<<<NN, th, 0, stream>>>(feat, al, ar, el8, er8, F, HF, lgG);
    stats8_k<<<NN, 64, 0, stream>>>(indptr, srcC, el8, er8, alpha8);
    agg8_k<<<NN, th, 0, stream>>>(feat, alpha8, indptr, srcC, bb, d_out, hbuf,
                                  F, HF, lgG, mode, flag);
  };

  layer(nodeb, 512, 256, W1t, al1b, ar1b, b1b, 0);
  layer(hbuf, 256, 256, W2t, al2b, ar2b, b2b, 0);
  layer(hbuf, 256, 512, W3t, al3b, ar3b, b3b, 1);
}